// Round 1
// baseline (498.377 us; speedup 1.0000x reference)
//
#include <hip/hip_runtime.h>
#include <math.h>

#define NH    8
#define HD    64
#define NTOK  4096   // D*H*W = 16^3
#define CDIM  512
#define NSAMP 27

// ============ Kernel 1: qkv = x @ w_qkv^T, scattered to q/k/v head-major ============
__global__ __launch_bounds__(256) void k_qkv(const float* __restrict__ A,
                                             const float* __restrict__ Wt,
                                             float* __restrict__ qb,
                                             float* __restrict__ kb,
                                             float* __restrict__ vb) {
  __shared__ float As[8][128];
  __shared__ float Bs[8][128];
  const int bm = blockIdx.x, bn = blockIdx.y;
  const int tid = threadIdx.x;
  const int tx = tid & 15, ty = tid >> 4;
  float acc[8][8];
#pragma unroll
  for (int i = 0; i < 8; i++)
#pragma unroll
    for (int j = 0; j < 8; j++) acc[i][j] = 0.f;
  const int r = tid >> 1, c4 = (tid & 1) * 4;
  for (int k0 = 0; k0 < 512; k0 += 8) {
    float4 a4 = *(const float4*)&A[(size_t)(bm * 128 + r) * 512 + k0 + c4];
    float4 b4 = *(const float4*)&Wt[(size_t)(bn * 128 + r) * 512 + k0 + c4];
    As[c4 + 0][r] = a4.x; As[c4 + 1][r] = a4.y; As[c4 + 2][r] = a4.z; As[c4 + 3][r] = a4.w;
    Bs[c4 + 0][r] = b4.x; Bs[c4 + 1][r] = b4.y; Bs[c4 + 2][r] = b4.z; Bs[c4 + 3][r] = b4.w;
    __syncthreads();
#pragma unroll
    for (int kk = 0; kk < 8; kk++) {
      float4 a0 = *(const float4*)&As[kk][ty * 8];
      float4 a1 = *(const float4*)&As[kk][ty * 8 + 4];
      float4 b0 = *(const float4*)&Bs[kk][tx * 4];        // split cols: tx*4 and 64+tx*4
      float4 b1 = *(const float4*)&Bs[kk][64 + tx * 4];   // avoids 4-way LDS bank conflict
      float av[8] = {a0.x, a0.y, a0.z, a0.w, a1.x, a1.y, a1.z, a1.w};
      float bv[8] = {b0.x, b0.y, b0.z, b0.w, b1.x, b1.y, b1.z, b1.w};
#pragma unroll
      for (int i = 0; i < 8; i++)
#pragma unroll
        for (int j = 0; j < 8; j++) acc[i][j] += av[i] * bv[j];
    }
    __syncthreads();
  }
#pragma unroll
  for (int i = 0; i < 8; i++) {
    int n = bm * 128 + ty * 8 + i;
#pragma unroll
    for (int j = 0; j < 8; j++) {
      int m = bn * 128 + ((j < 4) ? (tx * 4 + j) : (64 + tx * 4 + (j - 4)));
      int t = m >> 9;          // 0:q 1:k 2:v
      int h = (m >> 6) & 7;
      int d = m & 63;
      float* dst = (t == 0) ? qb : (t == 1) ? kb : vb;
      dst[((size_t)h * NTOK + n) * 64 + d] = acc[i][j];
    }
  }
}

// ============ Kernel 2: offsets obuf[h][n][j] = x_chunk(n,h) . w_off[j] ============
__global__ __launch_bounds__(256) void k_off(const float* __restrict__ x,
                                             const float* __restrict__ w_off,
                                             float* __restrict__ obuf) {
  __shared__ float xs[512];
  __shared__ float wsT[64][81];
  const int n = blockIdx.x;
  const int tid = threadIdx.x;
  xs[tid] = x[(size_t)n * 512 + tid];
  xs[tid + 256] = x[(size_t)n * 512 + tid + 256];
  for (int t = tid; t < 81 * 64; t += 256) {
    int j = t >> 6, d = t & 63;
    wsT[d][j] = w_off[t];
  }
  __syncthreads();
  for (int m = tid; m < NH * 81; m += 256) {
    int h = m / 81, j = m - h * 81;
    float acc = 0.f;
#pragma unroll
    for (int d = 0; d < 64; d++) acc += xs[h * 64 + d] * wsT[d][j];
    obuf[((size_t)h * NTOK + n) * 81 + j] = acc;
  }
}

// ============ Kernel 3: P[h][n][j] = q . concat(rel_w, rel_h, rel_d)[j] ============
__global__ __launch_bounds__(256) void k_pos(const float* __restrict__ qb,
                                             const float* __restrict__ rel_d,
                                             const float* __restrict__ rel_h,
                                             const float* __restrict__ rel_w,
                                             float* __restrict__ Pbuf) {
  __shared__ float qs[512];
  __shared__ float relT[64][128];   // cols 0..41 rel_w, 42..83 rel_h, 84..125 rel_d
  const int n = blockIdx.x;
  const int tid = threadIdx.x;
  {
    int h = tid >> 6, d = tid & 63;
    qs[tid] = qb[((size_t)h * NTOK + n) * 64 + d];
    int h2 = (tid + 256) >> 6;
    qs[tid + 256] = qb[((size_t)h2 * NTOK + n) * 64 + d];
  }
  for (int t = tid; t < 42 * 64; t += 256) {
    int j = t >> 6, d = t & 63;
    relT[d][j]      = rel_w[t];
    relT[d][42 + j] = rel_h[t];
    relT[d][84 + j] = rel_d[t];
  }
  __syncthreads();
  for (int m = tid; m < NH * 126; m += 256) {
    int h = m / 126, j = m - h * 126;
    float acc = 0.f;
#pragma unroll
    for (int d = 0; d < 64; d++) acc += qs[h * 64 + d] * relT[d][j];
    Pbuf[((size_t)h * NTOK + n) * 126 + j] = acc;
  }
}

// ============ Kernel 4: fused deformable attention (one wave per (h,n)) ============
__global__ __launch_bounds__(256) void k_attn(const float* __restrict__ qb,
                                              const float* __restrict__ kb,
                                              const float* __restrict__ vb,
                                              const float* __restrict__ obuf,
                                              const float* __restrict__ Pbuf,
                                              float* __restrict__ attb) {
  __shared__ int   s_idx[4][NSAMP][8];
  __shared__ float s_cw[4][NSAMP][8];
  __shared__ float s_w[4][NSAMP];
  const int bid = blockIdx.x;
  const int h = bid & 7;                  // head fast-varying -> per-XCD L2 locality
  const int wave = threadIdx.x >> 6;
  const int lane = threadIdx.x & 63;
  const int n = (bid >> 3) * 4 + wave;
  const int z = n >> 8, y = (n >> 4) & 15, xq = n & 15;
  const float qd = qb[((size_t)h * NTOK + n) * 64 + lane];

  if (lane < NSAMP) {
    const int s = lane;
    const float* op = &obuf[((size_t)h * NTOK + n) * 81 + s * 3];
    float oz = op[0], oy = op[1], ox = op[2];
    float pz = (float)(z + (s / 9) - 1) + oz;
    float py = (float)(y + ((s / 3) % 3) - 1) + oy;
    float px = (float)(xq + (s % 3) - 1) + ox;
    float fz = floorf(pz), fy = floorf(py), fx = floorf(px);
    float wz = pz - fz, wy = py - fy, wx = px - fx;
    int z0 = (int)fz, y0 = (int)fy, x0 = (int)fx;
#pragma unroll
    for (int c = 0; c < 8; c++) {
      int dz = (c >> 2) & 1, dy = (c >> 1) & 1, dx = c & 1;
      int zi = z0 + dz, yi = y0 + dy, xi = x0 + dx;
      bool valid = (zi >= 0) && (zi < 16) && (yi >= 0) && (yi < 16) && (xi >= 0) && (xi < 16);
      float w = (dz ? wz : 1.f - wz) * (dy ? wy : 1.f - wy) * (dx ? wx : 1.f - wx);
      int zc = min(max(zi, 0), 15), yc = min(max(yi, 0), 15), xc = min(max(xi, 0), 15);
      s_idx[wave][s][c] = (zc * 16 + yc) * 16 + xc;
      s_cw[wave][s][c] = valid ? w : 0.f;
    }
  }
  __syncthreads();

  // ---- pass 1: logits = scale * (q . k_sample) ----
  const float* kbh = kb + (size_t)h * NTOK * 64 + lane;
  float mydot = 0.f;
  for (int s = 0; s < NSAMP; s++) {
    float acc = 0.f;
#pragma unroll
    for (int c = 0; c < 8; c++)
      acc += s_cw[wave][s][c] * kbh[(size_t)s_idx[wave][s][c] * 64];
    float p = qd * acc;
#pragma unroll
    for (int off = 32; off >= 1; off >>= 1) p += __shfl_xor(p, off, 64);
    if (lane == s) mydot = p;
  }

  // ---- softmax over 27 (lanes 0..26 hold logits) ----
  float l = -INFINITY;
  if (lane < NSAMP) {
    int j = 15 + lane - xq;
    int n2 = (z * 16 + xq) * 16 + y;   // q(z, x, y) for rel_h term
    int n3 = (xq * 16 + z) * 16 + y;   // q(x, z, y) for rel_d term
    float pos = Pbuf[((size_t)h * NTOK + n) * 126 + j]
              + Pbuf[((size_t)h * NTOK + n2) * 126 + 42 + j]
              + Pbuf[((size_t)h * NTOK + n3) * 126 + 84 + j];
    l = mydot * 0.125f + pos;
  }
  float mx = l;
#pragma unroll
  for (int off = 32; off >= 1; off >>= 1) mx = fmaxf(mx, __shfl_xor(mx, off, 64));
  float e = (lane < NSAMP) ? __expf(l - mx) : 0.f;
  float sum = e;
#pragma unroll
  for (int off = 32; off >= 1; off >>= 1) sum += __shfl_xor(sum, off, 64);
  if (lane < NSAMP) s_w[wave][lane] = e / sum;
  __syncthreads();

  // ---- pass 2: out = sum_s w_s * v_sample ----
  const float* vbh = vb + (size_t)h * NTOK * 64 + lane;
  float out = 0.f;
  for (int s = 0; s < NSAMP; s++) {
    float acc = 0.f;
#pragma unroll
    for (int c = 0; c < 8; c++)
      acc += s_cw[wave][s][c] * vbh[(size_t)s_idx[wave][s][c] * 64];
    out += s_w[wave][s] * acc;
  }
  attb[(size_t)n * 512 + h * 64 + lane] = out;
}

// ============ Kernel 5: out = attb @ w_proj^T + b_proj ============
__global__ __launch_bounds__(256) void k_proj(const float* __restrict__ A,
                                              const float* __restrict__ Wt,
                                              const float* __restrict__ bias,
                                              float* __restrict__ out) {
  __shared__ float As[8][128];
  __shared__ float Bs[8][128];
  const int bm = blockIdx.x, bn = blockIdx.y;
  const int tid = threadIdx.x;
  const int tx = tid & 15, ty = tid >> 4;
  float acc[8][8];
#pragma unroll
  for (int i = 0; i < 8; i++)
#pragma unroll
    for (int j = 0; j < 8; j++) acc[i][j] = 0.f;
  const int r = tid >> 1, c4 = (tid & 1) * 4;
  for (int k0 = 0; k0 < 512; k0 += 8) {
    float4 a4 = *(const float4*)&A[(size_t)(bm * 128 + r) * 512 + k0 + c4];
    float4 b4 = *(const float4*)&Wt[(size_t)(bn * 128 + r) * 512 + k0 + c4];
    As[c4 + 0][r] = a4.x; As[c4 + 1][r] = a4.y; As[c4 + 2][r] = a4.z; As[c4 + 3][r] = a4.w;
    Bs[c4 + 0][r] = b4.x; Bs[c4 + 1][r] = b4.y; Bs[c4 + 2][r] = b4.z; Bs[c4 + 3][r] = b4.w;
    __syncthreads();
#pragma unroll
    for (int kk = 0; kk < 8; kk++) {
      float4 a0 = *(const float4*)&As[kk][ty * 8];
      float4 a1 = *(const float4*)&As[kk][ty * 8 + 4];
      float4 b0 = *(const float4*)&Bs[kk][tx * 4];
      float4 b1 = *(const float4*)&Bs[kk][64 + tx * 4];
      float av[8] = {a0.x, a0.y, a0.z, a0.w, a1.x, a1.y, a1.z, a1.w};
      float bv[8] = {b0.x, b0.y, b0.z, b0.w, b1.x, b1.y, b1.z, b1.w};
#pragma unroll
      for (int i = 0; i < 8; i++)
#pragma unroll
        for (int j = 0; j < 8; j++) acc[i][j] += av[i] * bv[j];
    }
    __syncthreads();
  }
#pragma unroll
  for (int i = 0; i < 8; i++) {
    int n = bm * 128 + ty * 8 + i;
#pragma unroll
    for (int j = 0; j < 8; j++) {
      int m = bn * 128 + ((j < 4) ? (tx * 4 + j) : (64 + tx * 4 + (j - 4)));
      out[(size_t)n * 512 + m] = acc[i][j] + bias[m];
    }
  }
}

extern "C" void kernel_launch(void* const* d_in, const int* in_sizes, int n_in,
                              void* d_out, int out_size, void* d_ws, size_t ws_size,
                              hipStream_t stream) {
  const float* x      = (const float*)d_in[0];
  const float* w_qkv  = (const float*)d_in[1];
  const float* w_proj = (const float*)d_in[2];
  const float* b_proj = (const float*)d_in[3];
  const float* w_off  = (const float*)d_in[4];
  const float* rel_d  = (const float*)d_in[5];
  const float* rel_h  = (const float*)d_in[6];
  const float* rel_w  = (const float*)d_in[7];
  // D=H=W=16 are compile-time constants of this problem instance.

  float* ws   = (float*)d_ws;
  float* qb   = ws;                                  // 8*4096*64
  float* kb   = qb + (size_t)NH * NTOK * 64;
  float* vb   = kb + (size_t)NH * NTOK * 64;
  float* ob   = vb + (size_t)NH * NTOK * 64;         // 8*4096*81
  float* Pb   = ob + (size_t)NH * NTOK * 81;         // 8*4096*126
  float* attb = Pb + (size_t)NH * NTOK * 126;        // 4096*512
  float* out  = (float*)d_out;

  k_qkv <<<dim3(32, 12), dim3(256), 0, stream>>>(x, w_qkv, qb, kb, vb);
  k_off <<<dim3(4096),  dim3(256), 0, stream>>>(x, w_off, ob);
  k_pos <<<dim3(4096),  dim3(256), 0, stream>>>(qb, rel_d, rel_h, rel_w, Pb);
  k_attn<<<dim3(8192),  dim3(256), 0, stream>>>(qb, kb, vb, ob, Pb, attb);
  k_proj<<<dim3(32, 4), dim3(256), 0, stream>>>(attb, w_proj, b_proj, out);
}